// Round 7
// baseline (6280.891 us; speedup 1.0000x reference)
//
#include <hip/hip_runtime.h>
#include <stdint.h>

typedef __attribute__((ext_vector_type(4))) float f32x4;

constexpr float QK_SCALE = 0.08838834764831845f;  // 128^-0.5

// ===========================================================================
// All-fp32 pipeline (bf16 numerically forbidden: 8-step recursion amplifies
// per-step noise ~1e3-1e4; verified r3-r5). Graph identical to verified r3:
//   proj GEMM -> seq attention -> gate (fused here) -> memory GEMM -> out.
// Stack-memory collapse (verified r3): all K slots identical -> uniform
// memory attention -> Mq/Mk unused; read = PSUM * (Mm @ Mv_full).
// ===========================================================================

__global__ void k_init32(const float* __restrict__ xr, const float* __restrict__ xi,
                         float* __restrict__ Z, float* __restrict__ Mm,
                         float* __restrict__ PSUM){
  for (int i = blockIdx.x*blockDim.x + threadIdx.x; i < 8192*256; i += gridDim.x*blockDim.x){
    int n = i >> 8, d = i & 255;
    Z[i]  = (d < 128) ? xr[n*128 + d] : xi[n*128 + d - 128];
    Mm[i] = 0.f;
    if (i < 8192) PSUM[i] = 1.f;
  }
}

// ---------------- tiled fp32 GEMM (unchanged from verified r6) --------------
template<int EPI>
__launch_bounds__(256, 2)
__global__ void k_gemm32(const float* __restrict__ A, int nb,
                         const float* __restrict__ W0r, const float* __restrict__ W0i,
                         const float* __restrict__ W1r, const float* __restrict__ W1i,
                         const float* __restrict__ W2r, const float* __restrict__ W2i,
                         float* __restrict__ C, const float* __restrict__ PSUM,
                         const float* __restrict__ bias){
  __shared__ float As[32][132];   // [k][m], padded
  __shared__ float Bs[32][132];   // [k][n], padded
  const int bx = blockIdx.x % nb, by = blockIdx.x / nb;
  const int m0 = by << 7, n0 = bx << 7;
  const int tid = threadIdx.x;
  const int tx = tid & 15, ty = tid >> 4;
  const float* Wr = W0r; const float* Wi = W0i;
  if constexpr (EPI == 0){
    int sec = n0 >> 8;
    Wr = (sec == 0) ? W0r : (sec == 1) ? W1r : W2r;
    Wi = (sec == 0) ? W0i : (sec == 1) ? W1i : W2i;
  }
  const int hn = (n0 >> 7) & 1;
  float acc[8][8];
  #pragma unroll
  for (int i = 0; i < 8; ++i)
    #pragma unroll
    for (int j = 0; j < 8; ++j) acc[i][j] = 0.f;

  for (int kt = 0; kt < 8; ++kt){
    if (kt) __syncthreads();
    #pragma unroll
    for (int i = 0; i < 4; ++i){               // A tile: transpose-scatter
      int c = i*256 + tid;
      int row = c >> 3, k4 = c & 7;
      f32x4 v = *(const f32x4*)&A[(size_t)(m0 + row)*256 + kt*32 + k4*4];
      As[k4*4+0][row] = v.x; As[k4*4+1][row] = v.y;
      As[k4*4+2][row] = v.z; As[k4*4+3][row] = v.w;
    }
    #pragma unroll
    for (int i = 0; i < 4; ++i){               // B tile: on-the-fly Wfull
      int c = i*256 + tid;
      int k = c >> 5, n4 = c & 31;
      int gk = kt*32 + k;
      f32x4 v;
      if constexpr (EPI == 2){
        v = *(const f32x4*)&W0r[(size_t)gk*128 + n4*4];
      } else {
        int hk = gk >> 7, kk = gk & 127;
        const float* src = ((hk ^ hn) == 0) ? Wr : Wi;
        v = *(const f32x4*)&src[(size_t)kk*128 + n4*4];
        if (hk == 1 && hn == 0){ v.x = -v.x; v.y = -v.y; v.z = -v.z; v.w = -v.w; }
      }
      *(f32x4*)&Bs[k][n4*4] = v;
    }
    __syncthreads();
    #pragma unroll 8
    for (int k = 0; k < 32; ++k){
      float a[8], b[8];
      *(f32x4*)&a[0] = *(const f32x4*)&As[k][ty*8];
      *(f32x4*)&a[4] = *(const f32x4*)&As[k][ty*8 + 4];
      *(f32x4*)&b[0] = *(const f32x4*)&Bs[k][tx*8];
      *(f32x4*)&b[4] = *(const f32x4*)&Bs[k][tx*8 + 4];
      #pragma unroll
      for (int i = 0; i < 8; ++i)
        #pragma unroll
        for (int j = 0; j < 8; ++j) acc[i][j] += a[i]*b[j];
    }
  }
  #pragma unroll
  for (int i = 0; i < 8; ++i){
    const int row = m0 + ty*8 + i;
    const int col = n0 + tx*8;
    if constexpr (EPI == 0){
      *(f32x4*)&C[(size_t)row*768 + col]     = *(const f32x4*)&acc[i][0];
      *(f32x4*)&C[(size_t)row*768 + col + 4] = *(const f32x4*)&acc[i][4];
    } else if constexpr (EPI == 1){
      const float s = 0.1f * PSUM[row];
      f32x4 z0 = *(const f32x4*)&C[(size_t)row*256 + col];
      f32x4 z1 = *(const f32x4*)&C[(size_t)row*256 + col + 4];
      z0.x += s*acc[i][0]; z0.y += s*acc[i][1]; z0.z += s*acc[i][2]; z0.w += s*acc[i][3];
      z1.x += s*acc[i][4]; z1.y += s*acc[i][5]; z1.z += s*acc[i][6]; z1.w += s*acc[i][7];
      *(f32x4*)&C[(size_t)row*256 + col]     = z0;
      *(f32x4*)&C[(size_t)row*256 + col + 4] = z1;
    } else {
      f32x4 b0 = *(const f32x4*)&bias[col];
      f32x4 b1 = *(const f32x4*)&bias[col + 4];
      f32x4 o0 = {acc[i][0]+b0.x, acc[i][1]+b0.y, acc[i][2]+b0.z, acc[i][3]+b0.w};
      f32x4 o1 = {acc[i][4]+b1.x, acc[i][5]+b1.y, acc[i][6]+b1.z, acc[i][7]+b1.w};
      *(f32x4*)&C[(size_t)row*128 + col]     = o0;
      *(f32x4*)&C[(size_t)row*128 + col + 4] = o1;
    }
  }
}

// ---------------- fp32 flash attention v2 + fused gate ----------------------
// 512 thr (8 waves): waves 0-3 = keys [0,512), waves 4-7 = [512,1024), each
// with independent online softmax; in-block merge via LDS. Natural layouts,
// XOR slot-swizzle (slot ^= row&15) -> conflicts <= 2-way. P in registers,
// PV reads P via __shfl. Gate/Mm/PSUM update fused into the epilogue.
// LDS = 32K (Qs) + 32K (KV dbl) = exactly 64 KB.
__launch_bounds__(512, 2)
__global__ void k_attn32(const float* __restrict__ QKV, float* __restrict__ ZF,
                         float* __restrict__ Mm, float* __restrict__ PSUM,
                         const float* __restrict__ Wc, const float* __restrict__ bc){
  __shared__ float Qs[32][256];     // swizzled [q][d]; reused as merge buffer
  __shared__ float KVs[2][64][64];  // per-half K then V chunks, swizzled
  const int tid = threadIdx.x;
  const int half = tid >> 8;
  const int s = tid & 255;
  const int tx = s & 15, ty = s >> 4;
  const int lane = tid & 63;
  const int batch = blockIdx.x & 7, qt = blockIdx.x >> 3;   // XCD-affine batch
  const int nbase = batch*1024 + qt*32;
  const int kv0 = batch*1024;

  #pragma unroll
  for (int i = 0; i < 4; ++i){      // stage Q (coalesced, swizzled slots)
    const int q = tid >> 4;         // 0..31
    const int d4 = (tid & 15) + 16*i;
    const int ph = (d4 & 48) | ((d4 & 15) ^ (q & 15));
    *(f32x4*)&Qs[q][ph*4] = *(const f32x4*)&QKV[(size_t)(nbase + q)*768 + d4*4];
  }
  const int q0 = ty*2, q1 = q0 + 1;
  const int sw0 = q0 & 15, sw1 = q1 & 15;
  float O[2][16];
  #pragma unroll
  for (int j = 0; j < 2; ++j)
    #pragma unroll
    for (int e = 0; e < 16; ++e) O[j][e] = 0.f;
  float mr[2] = {-3.0e30f, -3.0e30f}, lr[2] = {0.f, 0.f};

  for (int t = 0; t < 8; ++t){
    const int kb = kv0 + (half*8 + t)*64;
    float S[2][4] = {{0.f,0.f,0.f,0.f},{0.f,0.f,0.f,0.f}};
    for (int dc = 0; dc < 4; ++dc){
      __syncthreads();
      #pragma unroll
      for (int i = 0; i < 4; ++i){  // stage K chunk (coalesced, swizzled)
        const int c = i*256 + s;
        const int k = c >> 4, d4c = c & 15;
        *(f32x4*)&KVs[half][k][(d4c ^ (k & 15))*4] =
            *(const f32x4*)&QKV[(size_t)(kb + k)*768 + 256 + dc*64 + d4c*4];
      }
      __syncthreads();
      #pragma unroll 4
      for (int d4c = 0; d4c < 16; ++d4c){
        const f32x4 a0 = *(const f32x4*)&Qs[q0][(dc*16 + (d4c ^ sw0))*4];
        const f32x4 a1 = *(const f32x4*)&Qs[q1][(dc*16 + (d4c ^ sw1))*4];
        #pragma unroll
        for (int e = 0; e < 4; ++e){
          const f32x4 b = *(const f32x4*)&KVs[half][e*16 + tx][(d4c ^ tx)*4];
          S[0][e] += a0.x*b.x + a0.y*b.y + a0.z*b.z + a0.w*b.w;
          S[1][e] += a1.x*b.x + a1.y*b.y + a1.z*b.z + a1.w*b.w;
        }
      }
    }
    float pp[2][4];
    #pragma unroll
    for (int j = 0; j < 2; ++j){    // online softmax per q row
      #pragma unroll
      for (int e = 0; e < 4; ++e) S[j][e] *= QK_SCALE;
      float tm = fmaxf(fmaxf(S[j][0], S[j][1]), fmaxf(S[j][2], S[j][3]));
      tm = fmaxf(tm, __shfl_xor(tm, 1));
      tm = fmaxf(tm, __shfl_xor(tm, 2));
      tm = fmaxf(tm, __shfl_xor(tm, 4));
      tm = fmaxf(tm, __shfl_xor(tm, 8));
      const float mn = fmaxf(mr[j], tm);
      const float al = expf(mr[j] - mn);
      float rs = 0.f;
      #pragma unroll
      for (int e = 0; e < 4; ++e){ pp[j][e] = expf(S[j][e] - mn); rs += pp[j][e]; }
      rs += __shfl_xor(rs, 1); rs += __shfl_xor(rs, 2);
      rs += __shfl_xor(rs, 4); rs += __shfl_xor(rs, 8);
      lr[j] = lr[j]*al + rs;
      mr[j] = mn;
      #pragma unroll
      for (int e = 0; e < 16; ++e) O[j][e] *= al;
    }
    for (int dc = 0; dc < 4; ++dc){
      __syncthreads();
      #pragma unroll
      for (int i = 0; i < 4; ++i){  // stage V chunk
        const int c = i*256 + s;
        const int k = c >> 4, d4c = c & 15;
        *(f32x4*)&KVs[half][k][(d4c ^ (k & 15))*4] =
            *(const f32x4*)&QKV[(size_t)(kb + k)*768 + 512 + dc*64 + d4c*4];
      }
      __syncthreads();
      #pragma unroll
      for (int e2 = 0; e2 < 4; ++e2){
        #pragma unroll
        for (int kk = 0; kk < 16; ++kk){
          const int src = (lane & 48) | kk;
          const float p0 = __shfl(pp[0][e2], src);
          const float p1 = __shfl(pp[1][e2], src);
          const f32x4 v = *(const f32x4*)&KVs[half][e2*16 + kk][(tx ^ kk)*4];
          O[0][dc*4+0] += p0*v.x; O[0][dc*4+1] += p0*v.y;
          O[0][dc*4+2] += p0*v.z; O[0][dc*4+3] += p0*v.w;
          O[1][dc*4+0] += p1*v.x; O[1][dc*4+1] += p1*v.y;
          O[1][dc*4+2] += p1*v.z; O[1][dc*4+3] += p1*v.w;
        }
      }
    }
  }
  // ---- merge the two key-halves ----
  __syncthreads();                  // last KVs reads done; alias as Ml
  float* Ml = (float*)KVs;          // [half*64 + q*2 + {m,l}]
  if (tx == 0){
    Ml[half*64 + q0*2 + 0] = mr[0]; Ml[half*64 + q0*2 + 1] = lr[0];
    Ml[half*64 + q1*2 + 0] = mr[1]; Ml[half*64 + q1*2 + 1] = lr[1];
  }
  __syncthreads();
  float scv[2], lcv[2];
  #pragma unroll
  for (int j = 0; j < 2; ++j){
    const int q = ty*2 + j;
    const float M0 = Ml[q*2], L0 = Ml[q*2 + 1];
    const float M1 = Ml[64 + q*2], L1 = Ml[64 + q*2 + 1];
    const float mc = fmaxf(M0, M1);
    const float s0 = expf(M0 - mc), s1 = expf(M1 - mc);
    lcv[j] = s0*L0 + s1*L1;
    scv[j] = half ? s1 : s0;
  }
  if (half == 1){                   // deposit scaled partial into dead Qs
    #pragma unroll
    for (int j = 0; j < 2; ++j)
      #pragma unroll
      for (int dc = 0; dc < 4; ++dc){
        f32x4 w = {scv[j]*O[j][dc*4+0], scv[j]*O[j][dc*4+1],
                   scv[j]*O[j][dc*4+2], scv[j]*O[j][dc*4+3]};
        *(f32x4*)&Qs[ty*2+j][dc*64 + tx*4] = w;
      }
  }
  __syncthreads();
  if (half == 0){                   // finalize + fused gate/memory/pointer
    #pragma unroll
    for (int j = 0; j < 2; ++j){
      const int q = ty*2 + j;
      const float inv = 1.f / lcv[j];
      float z[16];
      #pragma unroll
      for (int dc = 0; dc < 4; ++dc){
        const f32x4 o1 = *(const f32x4*)&Qs[q][dc*64 + tx*4];
        z[dc*4+0] = (scv[j]*O[j][dc*4+0] + o1.x)*inv;
        z[dc*4+1] = (scv[j]*O[j][dc*4+1] + o1.y)*inv;
        z[dc*4+2] = (scv[j]*O[j][dc*4+2] + o1.z)*inv;
        z[dc*4+3] = (scv[j]*O[j][dc*4+3] + o1.w)*inv;
      }
      float d0 = 0.f, d1 = 0.f, d2 = 0.f;
      #pragma unroll
      for (int dc = 0; dc < 4; ++dc)
        #pragma unroll
        for (int e = 0; e < 4; ++e){
          const int dim = dc*64 + tx*4 + e;
          const float zz = z[dc*4+e];
          d0 += zz*Wc[dim*3 + 0]; d1 += zz*Wc[dim*3 + 1]; d2 += zz*Wc[dim*3 + 2];
        }
      d0 += __shfl_xor(d0,1); d0 += __shfl_xor(d0,2); d0 += __shfl_xor(d0,4); d0 += __shfl_xor(d0,8);
      d1 += __shfl_xor(d1,1); d1 += __shfl_xor(d1,2); d1 += __shfl_xor(d1,4); d1 += __shfl_xor(d1,8);
      d2 += __shfl_xor(d2,1); d2 += __shfl_xor(d2,2); d2 += __shfl_xor(d2,4); d2 += __shfl_xor(d2,8);
      const float g0 = 1.f/(1.f + expf(-(d0 + bc[0])));
      const float g1 = 1.f/(1.f + expf(-(d1 + bc[1])));
      const float g2 = 1.f/(1.f + expf(-(d2 + bc[2])));
      const float tt = g0 + g1 + g2, tot = tt + 1e-6f;
      const float push = g0/tot, fac = tt/tot;
      if (tx == 0) PSUM[nbase + q] *= fac;
      #pragma unroll
      for (int dc = 0; dc < 4; ++dc){
        const size_t idx = (size_t)(nbase + q)*256 + dc*64 + tx*4;
        f32x4 mo = *(const f32x4*)&Mm[idx];
        mo.x += push*(z[dc*4+0] - mo.x);
        mo.y += push*(z[dc*4+1] - mo.y);
        mo.z += push*(z[dc*4+2] - mo.z);
        mo.w += push*(z[dc*4+3] - mo.w);
        *(f32x4*)&Mm[idx] = mo;
        f32x4 w = {z[dc*4+0], z[dc*4+1], z[dc*4+2], z[dc*4+3]};
        *(f32x4*)&ZF[idx] = w;
      }
    }
  }
}

// ---------------------------------------------------------------------------
extern "C" void kernel_launch(void* const* d_in, const int* in_sizes, int n_in,
                              void* d_out, int out_size, void* d_ws, size_t ws_size,
                              hipStream_t stream){
  (void)in_sizes; (void)n_in; (void)out_size; (void)ws_size;
  const float* xr   = (const float*)d_in[0];
  const float* xi   = (const float*)d_in[1];
  const float* Wq_r = (const float*)d_in[2];
  const float* Wq_i = (const float*)d_in[3];
  const float* Wk_r = (const float*)d_in[4];
  const float* Wk_i = (const float*)d_in[5];
  const float* Wv_r = (const float*)d_in[6];
  const float* Wv_i = (const float*)d_in[7];
  // d_in[8..11] (Mq_*, Mk_*) unused: all stack slots identical -> memory
  // attention exactly uniform regardless of its q/k projections (verified r3).
  const float* Mv_r = (const float*)d_in[12];
  const float* Mv_i = (const float*)d_in[13];
  const float* Wc   = (const float*)d_in[14];
  const float* bc   = (const float*)d_in[15];
  const float* Wo   = (const float*)d_in[16];
  const float* bo   = (const float*)d_in[17];

  // Workspace layout identical to verified round 3/6 (41,975,808 B).
  uint8_t* w = (uint8_t*)d_ws;
  float* Z    = (float*)w; w += (size_t)8192*256*4;   // state; aliased as ZF
  float* QKV  = (float*)w; w += (size_t)8192*768*4;
  float* Mm   = (float*)w; w += (size_t)8192*256*4;
  float* PSUM = (float*)w; w += (size_t)8192*4;
  float* ZF   = Z;  // safe alias: state dead once proj consumed it.

  k_init32<<<dim3(1024), dim3(256), 0, stream>>>(xr, xi, Z, Mm, PSUM);
  for (int t = 0; t < 8; ++t){
    k_gemm32<0><<<dim3(384), dim3(256), 0, stream>>>(Z, 6,
        Wq_r, Wq_i, Wk_r, Wk_i, Wv_r, Wv_i, QKV, nullptr, nullptr);
    k_attn32<<<dim3(256), dim3(512), 0, stream>>>(QKV, ZF, Mm, PSUM, Wc, bc);
    k_gemm32<1><<<dim3(128), dim3(256), 0, stream>>>(Mm, 2,
        Mv_r, Mv_i, nullptr, nullptr, nullptr, nullptr, Z, PSUM, nullptr);
  }
  k_gemm32<2><<<dim3(64), dim3(256), 0, stream>>>(Z, 1,
      Wo, nullptr, nullptr, nullptr, nullptr, nullptr, (float*)d_out, nullptr, bo);
}